// Round 11
// baseline (10461.737 us; speedup 1.0000x reference)
//
#include <hip/hip_runtime.h>
#include <hip/hip_bf16.h>
#include <stdint.h>

#define T_STEPS 12
#define NN 20000
#define NE 320000
#define FIN 128
#define HD 256
#define FOUT 128

typedef __attribute__((ext_vector_type(4))) float f32x4;
typedef __attribute__((ext_vector_type(8))) _Float16 f16x8;

static __device__ __forceinline__ float sigmoidf_(float x) {
  return 1.0f / (1.0f + __expf(-x));
}
static __device__ __forceinline__ ushort f2h(float f) {
  union { ushort s; _Float16 h; } v; v.h = (_Float16)f; return v.s;
}

// ---------------- CSR build ----------------
__global__ void count_kernel(const int* __restrict__ dst, int* __restrict__ counts) {
  int e = blockIdx.x * blockDim.x + threadIdx.x;
  if (e < NE) atomicAdd(&counts[dst[e]], 1);
}

__global__ void scan_kernel(const int* __restrict__ counts, int* __restrict__ offs,
                            int* __restrict__ cursor) {
  __shared__ int sm[1024];
  __shared__ int carry_s;
  if (threadIdx.x == 0) carry_s = 0;
  __syncthreads();
  const int n = NN;
  int nch = (n + 1023) >> 10;
  for (int c = 0; c < nch; ++c) {
    int i = (c << 10) + (int)threadIdx.x;
    int v = (i < n) ? counts[i] : 0;
    sm[threadIdx.x] = v;
    __syncthreads();
    for (int off = 1; off < 1024; off <<= 1) {
      int t = (threadIdx.x >= (unsigned)off) ? sm[threadIdx.x - off] : 0;
      __syncthreads();
      sm[threadIdx.x] += t;
      __syncthreads();
    }
    int incl = sm[threadIdx.x];
    int carry_local = carry_s;
    if (i < n) {
      int excl = carry_local + incl - v;
      offs[i] = excl;
      cursor[i] = excl;
    }
    __syncthreads();
    if (threadIdx.x == 1023) carry_s = carry_local + incl;
    __syncthreads();
  }
  if (threadIdx.x == 0) offs[n] = carry_s;
}

__global__ void fill_kernel(const int* __restrict__ src, const int* __restrict__ dst,
                            int* __restrict__ cursor, int* __restrict__ esrc) {
  int e = blockIdx.x * blockDim.x + threadIdx.x;
  if (e < NE) {
    int d = dst[e];
    int pos = atomicAdd(&cursor[d], 1);
    esrc[pos] = src[e];
  }
}

// ---------------- agg body: fp32 gather-sum -> fp16 hi/lo (W=256, out ld=512) ----------------
static __device__ __forceinline__ void agg_body256(int blk, const float* __restrict__ feat,
                                                   const int* __restrict__ offs,
                                                   const int* __restrict__ esrc,
                                                   _Float16* __restrict__ out) {
  int d = blk * 4 + (threadIdx.x >> 6);
  int lane = threadIdx.x & 63;
  int beg = offs[d], end = offs[d + 1];
  float a0[4] = {}, a1[4] = {}, a2[4] = {}, a3[4] = {};
  int e = beg;
  for (; e + 3 < end; e += 4) {
    float4 v0 = *reinterpret_cast<const float4*>(feat + (size_t)esrc[e] * 256 + lane * 4);
    float4 v1 = *reinterpret_cast<const float4*>(feat + (size_t)esrc[e + 1] * 256 + lane * 4);
    float4 v2 = *reinterpret_cast<const float4*>(feat + (size_t)esrc[e + 2] * 256 + lane * 4);
    float4 v3 = *reinterpret_cast<const float4*>(feat + (size_t)esrc[e + 3] * 256 + lane * 4);
    a0[0] += v0.x; a0[1] += v0.y; a0[2] += v0.z; a0[3] += v0.w;
    a1[0] += v1.x; a1[1] += v1.y; a1[2] += v1.z; a1[3] += v1.w;
    a2[0] += v2.x; a2[1] += v2.y; a2[2] += v2.z; a2[3] += v2.w;
    a3[0] += v3.x; a3[1] += v3.y; a3[2] += v3.z; a3[3] += v3.w;
  }
  for (; e < end; ++e) {
    float4 v0 = *reinterpret_cast<const float4*>(feat + (size_t)esrc[e] * 256 + lane * 4);
    a0[0] += v0.x; a0[1] += v0.y; a0[2] += v0.z; a0[3] += v0.w;
  }
  ushort hi[4], lo[4];
#pragma unroll
  for (int p = 0; p < 4; ++p) {
    float a = (a0[p] + a1[p]) + (a2[p] + a3[p]);
    hi[p] = f2h(a);
    union { ushort s; _Float16 h; } u; u.s = hi[p];
    lo[p] = f2h(a - (float)u.h);
  }
  *reinterpret_cast<ushort4*>(out + (size_t)d * 512 + lane * 4) = *reinterpret_cast<ushort4*>(hi);
  *reinterpret_cast<ushort4*>(out + (size_t)d * 512 + 256 + lane * 4) = *reinterpret_cast<ushort4*>(lo);
}

// standalone agg (low VGPR, no LDS -> high occupancy)
__global__ void agg_split_h(const float* __restrict__ feat, const int* __restrict__ offs,
                            const int* __restrict__ esrc, _Float16* __restrict__ out) {
  agg_body256(blockIdx.x, feat, offs, esrc, out);
}

// dual agg: grid (NN/4, 2) — two independent gathers in one launch (agg∥agg only)
__global__ void agg_dual(const float* __restrict__ f0, _Float16* __restrict__ o0,
                         const float* __restrict__ f1, _Float16* __restrict__ o1,
                         const int* __restrict__ offs, const int* __restrict__ esrc) {
  if (blockIdx.y == 0) agg_body256(blockIdx.x, f0, offs, esrc, o0);
  else                 agg_body256(blockIdx.x, f1, offs, esrc, o1);
}

// batched x-aggregation over all T steps: grid (NN/4, T); out [t][N][256] = [hi128|lo128]
__global__ void agg_split_x(const float* __restrict__ x, const int* __restrict__ offs,
                            const int* __restrict__ esrc, _Float16* __restrict__ out) {
  int t = blockIdx.y;
  const float* feat = x + (size_t)t * NN * FIN;
  _Float16* o = out + (size_t)t * NN * 256;
  int d = blockIdx.x * 4 + (threadIdx.x >> 6);
  int lane = threadIdx.x & 63;
  int beg = offs[d], end = offs[d + 1];
  float a0[2] = {}, a1[2] = {}, a2[2] = {}, a3[2] = {};
  int e = beg;
  for (; e + 3 < end; e += 4) {
    float2 v0 = *reinterpret_cast<const float2*>(feat + (size_t)esrc[e] * FIN + lane * 2);
    float2 v1 = *reinterpret_cast<const float2*>(feat + (size_t)esrc[e + 1] * FIN + lane * 2);
    float2 v2 = *reinterpret_cast<const float2*>(feat + (size_t)esrc[e + 2] * FIN + lane * 2);
    float2 v3 = *reinterpret_cast<const float2*>(feat + (size_t)esrc[e + 3] * FIN + lane * 2);
    a0[0] += v0.x; a0[1] += v0.y; a1[0] += v1.x; a1[1] += v1.y;
    a2[0] += v2.x; a2[1] += v2.y; a3[0] += v3.x; a3[1] += v3.y;
  }
  for (; e < end; ++e) {
    float2 v0 = *reinterpret_cast<const float2*>(feat + (size_t)esrc[e] * FIN + lane * 2);
    a0[0] += v0.x; a0[1] += v0.y;
  }
  float s0 = (a0[0] + a1[0]) + (a2[0] + a3[0]);
  float s1 = (a0[1] + a1[1]) + (a2[1] + a3[1]);
  ushort2 hi, lo;
  hi.x = f2h(s0); hi.y = f2h(s1);
  union { ushort s; _Float16 h; } u0, u1;
  u0.s = hi.x; u1.s = hi.y;
  lo.x = f2h(s0 - (float)u0.h); lo.y = f2h(s1 - (float)u1.h);
  *reinterpret_cast<ushort2*>(o + (size_t)d * 256 + lane * 2) = hi;
  *reinterpret_cast<ushort2*>(o + (size_t)d * 256 + FIN + lane * 2) = lo;
}

// ---------------- GEMM params + body (identical math to round 9) ----------------
// mode 0: C = acc + bias.
// mode 1 (fused r/u): v = acc + (Cacc ? Cacc_row : bias); cols<256 -> rh=sigmoid(v)*h;
//         256..511 -> C=sigmoid(v); >=512 -> C=v.
// mode 2 (fused c + state update): nh = u*h + (1-u)*tanh(xw_c + acc); writes h (+hf).
struct GemmP {
  const _Float16* Aa; int lda_a, wrapA, lenA;
  const _Float16* Ab; int lda_b, wrapB;
  const _Float16* B; int ldb;
  float* C; int ldc;
  const float* bias;
  const float* Cacc;
  int M, K, mode;
  float* h; _Float16* hf; float* rh;
  int nch, rpg;
};

static __device__ void gemm_body(int p, const GemmP g, _Float16* As, _Float16* Bs) {
  int xcd = p & 7;
  int q = p >> 3;
  int rowt = xcd * g.rpg + q / g.nch;
  int chunk = q % g.nch;
  int m0 = rowt * 128;
  if (m0 >= g.M) return;
  int n0 = chunk * 128;

  int tid = threadIdx.x;
  int wave = tid >> 6;
  int lane = tid & 63;
  int wm = wave >> 1, wn = wave & 1;
  int lrow = lane & 15;
  int kgrp = lane >> 4;

  f32x4 acc[4][4] = {};

  int srow = tid >> 3;
  int skb = (tid & 7) * 16;

  uint4 av[4], bv[4];
  auto load_tile = [&](int k0) {
    const _Float16* Abase;
    int ka, ldA;
    if (k0 < g.lenA) {
      ka = (k0 >= g.wrapA) ? k0 - g.wrapA : k0;
      Abase = g.Aa; ldA = g.lda_a;
    } else {
      int kp = k0 - g.lenA;
      ka = (kp >= g.wrapB) ? kp - g.wrapB : kp;
      Abase = g.Ab; ldA = g.lda_b;
    }
#pragma unroll
    for (int p4 = 0; p4 < 4; ++p4) {
      int row = p4 * 32 + srow;
      int gr = m0 + row;
      av[p4] = (gr < g.M)
                   ? *reinterpret_cast<const uint4*>(&Abase[(size_t)gr * ldA + ka + (tid & 7) * 8])
                   : make_uint4(0, 0, 0, 0);
      bv[p4] = *reinterpret_cast<const uint4*>(&g.B[(size_t)(n0 + row) * g.ldb + k0 + (tid & 7) * 8]);
    }
  };

  load_tile(0);
  for (int k0 = 0; k0 < g.K; k0 += 64) {
    __syncthreads();
#pragma unroll
    for (int p4 = 0; p4 < 4; ++p4) {
      int row = p4 * 32 + srow;
      int off = row * 128 + (skb ^ ((row & 7) << 4));
      *reinterpret_cast<uint4*>(reinterpret_cast<char*>(As) + off) = av[p4];
      *reinterpret_cast<uint4*>(reinterpret_cast<char*>(Bs) + off) = bv[p4];
    }
    __syncthreads();
    if (k0 + 64 < g.K) load_tile(k0 + 64);

#pragma unroll
    for (int kk = 0; kk < 2; ++kk) {
      f16x8 af[4], bf[4];
      int kbyte = kk * 64 + kgrp * 16;
#pragma unroll
      for (int i = 0; i < 4; ++i) {
        int ar = wm * 64 + i * 16 + lrow;
        af[i] = *reinterpret_cast<const f16x8*>(
            reinterpret_cast<const char*>(As) + ar * 128 + (kbyte ^ ((ar & 7) << 4)));
        int br = wn * 64 + i * 16 + lrow;
        bf[i] = *reinterpret_cast<const f16x8*>(
            reinterpret_cast<const char*>(Bs) + br * 128 + (kbyte ^ ((br & 7) << 4)));
      }
#pragma unroll
      for (int i = 0; i < 4; ++i)
#pragma unroll
        for (int j = 0; j < 4; ++j)
          acc[i][j] = __builtin_amdgcn_mfma_f32_16x16x32_f16(bf[j], af[i], acc[i][j], 0, 0, 0);
    }
  }

#pragma unroll
  for (int i = 0; i < 4; ++i) {
    int m = m0 + wm * 64 + i * 16 + lrow;
    if (m >= g.M) continue;
#pragma unroll
    for (int j = 0; j < 4; ++j) {
      int colbase = n0 + wn * 64 + j * 16 + kgrp * 4;
      f32x4 v = acc[i][j];
      if (g.mode == 0) {
        float4 bv4 = *reinterpret_cast<const float4*>(&g.bias[colbase]);
        v[0] += bv4.x; v[1] += bv4.y; v[2] += bv4.z; v[3] += bv4.w;
        *reinterpret_cast<f32x4*>(&g.C[(size_t)m * g.ldc + colbase]) = v;
      } else if (g.mode == 1) {
        if (g.Cacc) {
          float4 a4 = *reinterpret_cast<const float4*>(&g.Cacc[(size_t)m * g.ldc + colbase]);
          v[0] += a4.x; v[1] += a4.y; v[2] += a4.z; v[3] += a4.w;
        } else {
          float4 bv4 = *reinterpret_cast<const float4*>(&g.bias[colbase]);
          v[0] += bv4.x; v[1] += bv4.y; v[2] += bv4.z; v[3] += bv4.w;
        }
        if (colbase < 256) {
          float4 hv = *reinterpret_cast<const float4*>(&g.h[(size_t)m * 256 + colbase]);
          f32x4 rv;
          rv[0] = sigmoidf_(v[0]) * hv.x;
          rv[1] = sigmoidf_(v[1]) * hv.y;
          rv[2] = sigmoidf_(v[2]) * hv.z;
          rv[3] = sigmoidf_(v[3]) * hv.w;
          *reinterpret_cast<f32x4*>(&g.rh[(size_t)m * 256 + colbase]) = rv;
        } else if (colbase < 512) {
          v[0] = sigmoidf_(v[0]); v[1] = sigmoidf_(v[1]);
          v[2] = sigmoidf_(v[2]); v[3] = sigmoidf_(v[3]);
          *reinterpret_cast<f32x4*>(&g.C[(size_t)m * g.ldc + colbase]) = v;
        } else {
          *reinterpret_cast<f32x4*>(&g.C[(size_t)m * g.ldc + colbase]) = v;
        }
      } else {
        float4 xc = *reinterpret_cast<const float4*>(&g.C[(size_t)m * g.ldc + 512 + colbase]);
        float4 uu = *reinterpret_cast<const float4*>(&g.C[(size_t)m * g.ldc + 256 + colbase]);
        float* hp = &g.h[(size_t)m * 256 + colbase];
        float4 hv = *reinterpret_cast<const float4*>(hp);
        float4 nh;
        nh.x = uu.x * hv.x + (1.f - uu.x) * tanhf(xc.x + v[0]);
        nh.y = uu.y * hv.y + (1.f - uu.y) * tanhf(xc.y + v[1]);
        nh.z = uu.z * hv.z + (1.f - uu.z) * tanhf(xc.z + v[2]);
        nh.w = uu.w * hv.w + (1.f - uu.w) * tanhf(xc.w + v[3]);
        *reinterpret_cast<float4*>(hp) = nh;
        if (g.hf) {
          ushort4 hv16;
          hv16.x = f2h(nh.x); hv16.y = f2h(nh.y);
          hv16.z = f2h(nh.z); hv16.w = f2h(nh.w);
          *reinterpret_cast<ushort4*>(&g.hf[(size_t)m * 256 + colbase]) = hv16;
        }
      }
    }
  }
}

// ---------------- combo: up to 3 GEMMs in one launch (GEMM∥GEMM only) ----------------
__global__ __launch_bounds__(256) void combo(GemmP ga, int nga, GemmP gb, int ngb,
                                             GemmP gc, int ngc) {
  __shared__ _Float16 As[128 * 64];
  __shared__ _Float16 Bs[128 * 64];
  int b = blockIdx.x;
  if (b < nga) { gemm_body(b, ga, As, Bs); return; }
  b -= nga;
  if (b < ngb) { gemm_body(b, gb, As, Bs); return; }
  b -= ngb;
  if (b < ngc) gemm_body(b, gc, As, Bs);
}

// ---------------- weight prep ----------------
__global__ void wtrans(const float* __restrict__ W, _Float16* __restrict__ dst,
                       int K, int ldw, int ldd, int koff, int mode) {
  int k = blockIdx.x * blockDim.x + threadIdx.x;
  int n = blockIdx.y;
  if (k < K) {
    float w = W[(size_t)k * ldw + n];
    _Float16 hi = (_Float16)w;
    dst[(size_t)n * ldd + koff + k] = mode ? (_Float16)(w - (float)hi) : hi;
  }
}

__global__ void bias_comb(const float* __restrict__ bx, const float* __restrict__ bh,
                          float* __restrict__ out) {
  int i = blockIdx.x * blockDim.x + threadIdx.x;
  if (i < 768) out[i] = bx[i] + bh[i];
}

__global__ void copy_kernel(const float* __restrict__ in, float* __restrict__ out, int n4) {
  int i = blockIdx.x * blockDim.x + threadIdx.x;
  if (i < n4) reinterpret_cast<float4*>(out)[i] = reinterpret_cast<const float4*>(in)[i];
}

// ---------------- host ----------------
extern "C" void kernel_launch(void* const* d_in, const int* in_sizes, int n_in,
                              void* d_out, int out_size, void* d_ws, size_t ws_size,
                              hipStream_t stream) {
  const float* x   = (const float*)d_in[0];
  const float* h0  = (const float*)d_in[1];
  const int*   src = (const int*)d_in[2];
  const int*   dst = (const int*)d_in[3];
  const float* Wx0 = (const float*)d_in[4];
  const float* bx0 = (const float*)d_in[5];
  const float* Wh0 = (const float*)d_in[6];
  const float* bh0 = (const float*)d_in[7];
  const float* Wx1 = (const float*)d_in[8];
  const float* bx1 = (const float*)d_in[9];
  const float* Wh1 = (const float*)d_in[10];
  const float* bh1 = (const float*)d_in[11];
  const float* Wo  = (const float*)d_in[12];
  const float* bo  = (const float*)d_in[13];
  float* out = (float*)d_out;

  char* p = (char*)d_ws;
  auto alloc = [&](size_t bytes) {
    char* r = p;
    p += (bytes + 255) & ~(size_t)255;
    return r;
  };
  int* offs   = (int*)alloc((NN + 1) * sizeof(int));
  int* cursor = (int*)alloc(NN * sizeof(int));
  int* counts = (int*)alloc(NN * sizeof(int));
  int* esrc   = (int*)alloc(NE * sizeof(int));
  _Float16* B0  = (_Float16*)alloc((size_t)768 * 1152 * 2);
  _Float16* B0h = (_Float16*)alloc((size_t)256 * 768 * 2);
  _Float16* B1  = (_Float16*)alloc((size_t)768 * 1536 * 2);
  _Float16* B1h = (_Float16*)alloc((size_t)256 * 768 * 2);
  _Float16* Bo  = (_Float16*)alloc((size_t)128 * 256 * 2);
  float* b0c  = (float*)alloc(768 * 4);
  float* b1c  = (float*)alloc(768 * 4);
  _Float16* XAGG  = (_Float16*)alloc((size_t)T_STEPS * NN * 256 * 2);
  _Float16* H0AGG = (_Float16*)alloc((size_t)NN * 512 * 2);
  _Float16* H1AGG = (_Float16*)alloc((size_t)NN * 512 * 2);
  _Float16* RHAGG = (_Float16*)alloc((size_t)NN * 512 * 2);
  _Float16* h1fA  = (_Float16*)alloc((size_t)NN * 256 * 2);  // h1f double buffer
  _Float16* h1fB  = (_Float16*)alloc((size_t)NN * 256 * 2);
  float* rhf  = (float*)alloc((size_t)NN * 256 * 4);
  float* xw0  = (float*)alloc((size_t)NN * 768 * 4);
  float* xw1  = (float*)alloc((size_t)NN * 768 * 4);

  float* h0c = out + (size_t)T_STEPS * NN * FOUT;
  float* h1c = h0c + (size_t)NN * HD;

  // CSR
  hipMemsetAsync(counts, 0, NN * sizeof(int), stream);
  count_kernel<<<(NE + 255) / 256, 256, 0, stream>>>(dst, counts);
  scan_kernel<<<1, 1024, 0, stream>>>(counts, offs, cursor);
  fill_kernel<<<(NE + 255) / 256, 256, 0, stream>>>(src, dst, cursor, esrc);

  // weight prep (3-term layout [Whi|Whi|Wlo] per source; c-rows h-part zero)
  hipMemsetAsync(B0, 0, (size_t)768 * 1152 * 2, stream);
  hipMemsetAsync(B1, 0, (size_t)768 * 1536 * 2, stream);
  for (int g = 0; g < 3; ++g) {
    const float* W = Wx0 + (size_t)g * 128 * 256;
    _Float16* D = B0 + (size_t)g * 256 * 1152;
    wtrans<<<dim3(1, 256), 256, 0, stream>>>(W, D, 128, 256, 1152, 0, 0);
    wtrans<<<dim3(1, 256), 256, 0, stream>>>(W, D, 128, 256, 1152, 128, 0);
    wtrans<<<dim3(1, 256), 256, 0, stream>>>(W, D, 128, 256, 1152, 256, 1);
  }
  for (int g = 0; g < 2; ++g) {
    const float* W = Wh0 + (size_t)g * 256 * 256;
    _Float16* D = B0 + (size_t)g * 256 * 1152;
    wtrans<<<dim3(1, 256), 256, 0, stream>>>(W, D, 256, 256, 1152, 384, 0);
    wtrans<<<dim3(1, 256), 256, 0, stream>>>(W, D, 256, 256, 1152, 640, 0);
    wtrans<<<dim3(1, 256), 256, 0, stream>>>(W, D, 256, 256, 1152, 896, 1);
  }
  {
    const float* W = Wh0 + (size_t)2 * 256 * 256;
    wtrans<<<dim3(1, 256), 256, 0, stream>>>(W, B0h, 256, 256, 768, 0, 0);
    wtrans<<<dim3(1, 256), 256, 0, stream>>>(W, B0h, 256, 256, 768, 256, 0);
    wtrans<<<dim3(1, 256), 256, 0, stream>>>(W, B0h, 256, 256, 768, 512, 1);
  }
  for (int g = 0; g < 3; ++g) {
    const float* W = Wx1 + (size_t)g * 256 * 256;
    _Float16* D = B1 + (size_t)g * 256 * 1536;
    wtrans<<<dim3(1, 256), 256, 0, stream>>>(W, D, 256, 256, 1536, 0, 0);
    wtrans<<<dim3(1, 256), 256, 0, stream>>>(W, D, 256, 256, 1536, 256, 0);
    wtrans<<<dim3(1, 256), 256, 0, stream>>>(W, D, 256, 256, 1536, 512, 1);
  }
  for (int g = 0; g < 2; ++g) {
    const float* W = Wh1 + (size_t)g * 256 * 256;
    _Float16* D = B1 + (size_t)g * 256 * 1536;
    wtrans<<<dim3(1, 256), 256, 0, stream>>>(W, D, 256, 256, 1536, 768, 0);
    wtrans<<<dim3(1, 256), 256, 0, stream>>>(W, D, 256, 256, 1536, 1024, 0);
    wtrans<<<dim3(1, 256), 256, 0, stream>>>(W, D, 256, 256, 1536, 1280, 1);
  }
  {
    const float* W = Wh1 + (size_t)2 * 256 * 256;
    wtrans<<<dim3(1, 256), 256, 0, stream>>>(W, B1h, 256, 256, 768, 0, 0);
    wtrans<<<dim3(1, 256), 256, 0, stream>>>(W, B1h, 256, 256, 768, 256, 0);
    wtrans<<<dim3(1, 256), 256, 0, stream>>>(W, B1h, 256, 256, 768, 512, 1);
  }
  wtrans<<<dim3(1, 128), 256, 0, stream>>>(Wo, Bo, 256, 128, 256, 0, 0);
  bias_comb<<<3, 256, 0, stream>>>(bx0, bh0, b0c);
  bias_comb<<<3, 256, 0, stream>>>(bx1, bh1, b1c);

  copy_kernel<<<(2 * NN * HD / 4 + 255) / 256, 256, 0, stream>>>(h0, h0c, 2 * NN * HD / 4);

  dim3 blk(256);
  const int RPG = 20;
  int g6 = 8 * RPG * 6, g2 = 8 * RPG * 2, g1 = 8 * RPG * 1;  // 960 / 320 / 160 (all %8==0)
  int agg_grid = NN / 4;

  agg_split_x<<<dim3(agg_grid, T_STEPS), blk, 0, stream>>>(x, offs, esrc, XAGG);
  agg_split_h<<<agg_grid, blk, 0, stream>>>(h0c, offs, esrc, H0AGG);

  GemmP empty = {};
  empty.M = 0; empty.nch = 1; empty.rpg = 1;

  for (int t = 0; t < T_STEPS; ++t) {
    _Float16* h1f_prev = ((t - 1) & 1) ? h1fB : h1fA;  // written by C1_{t-1}
    _Float16* h1f_cur  = (t & 1) ? h1fB : h1fA;        // written by C1_t (next step's A)

    // ---- A: C1_{t-1} (deferred) ∥ L0_t ----
    GemmP C1p = {RHAGG, 512, 512, 768, nullptr, 0, 0, B1h, 768, xw1, 768, nullptr, nullptr,
                 NN, 768, 2, h1c, h1f_prev, nullptr, 2, RPG};
    GemmP L0p = {XAGG + (size_t)t * NN * 256, 256, 256, 384, H0AGG, 512, 512,
                 B0, 1152, xw0, 768, b0c, nullptr, NN, 1152, 1, h0c, nullptr, rhf, 6, RPG};
    if (t == 0)
      combo<<<g6, blk, 0, stream>>>(L0p, g6, empty, 0, empty, 0);
    else
      combo<<<g2 + g6, blk, 0, stream>>>(C1p, g2, L0p, g6, empty, 0);

    // ---- B: agg(rhf→RHAGG) ∥ agg(h1c→H1AGG) ----
    agg_dual<<<dim3(agg_grid, 2), blk, 0, stream>>>(rhf, RHAGG, h1c, H1AGG, offs, esrc);

    // ---- C: C0_t ∥ L1a_t (Wh1 part → xw1) ∥ OP_{t-1} ----
    GemmP C0p = {RHAGG, 512, 512, 768, nullptr, 0, 0, B0h, 768, xw0, 768, nullptr, nullptr,
                 NN, 768, 2, h0c, nullptr, nullptr, 2, RPG};
    GemmP L1a = {H1AGG, 512, 512, 768, nullptr, 0, 0, B1 + 768, 1536, xw1, 768, b1c, nullptr,
                 NN, 768, 0, nullptr, nullptr, nullptr, 6, RPG};
    GemmP OPp = {h1f_prev, 256, 256, 256, nullptr, 0, 0, Bo, 256,
                 out + (size_t)(t > 0 ? t - 1 : 0) * NN * FOUT, FOUT, bo, nullptr,
                 NN, 256, 0, nullptr, nullptr, nullptr, 1, RPG};
    int ngc = (t > 0) ? g1 : 0;
    combo<<<g2 + g6 + ngc, blk, 0, stream>>>(C0p, g2, L1a, g6, OPp, ngc);

    // ---- D: agg(h0c→H0AGG)  (feeds L1b_t and L0_{t+1}) ----
    agg_split_h<<<agg_grid, blk, 0, stream>>>(h0c, offs, esrc, H0AGG);

    // ---- E: L1b_t (Wx1 part, accumulate xw1 in place, fused r/u) ----
    GemmP L1b = {H0AGG, 512, 512, 768, nullptr, 0, 0, B1, 1536, xw1, 768, nullptr, xw1,
                 NN, 768, 1, h1c, nullptr, rhf, 6, RPG};
    combo<<<g6, blk, 0, stream>>>(L1b, g6, empty, 0, empty, 0);

    // ---- F: agg(rhf→RHAGG)  (feeds C1_t in next step's A) ----
    agg_split_h<<<agg_grid, blk, 0, stream>>>(rhf, offs, esrc, RHAGG);
  }

  // epilogue: C1_{T-1} ∥ OP_{T-2}, then OP_{T-1}
  _Float16* h1f_last = ((T_STEPS - 1) & 1) ? h1fB : h1fA;
  _Float16* h1f_prev = ((T_STEPS - 2) & 1) ? h1fB : h1fA;
  GemmP C1f = {RHAGG, 512, 512, 768, nullptr, 0, 0, B1h, 768, xw1, 768, nullptr, nullptr,
               NN, 768, 2, h1c, h1f_last, nullptr, 2, RPG};
  GemmP OPm2 = {h1f_prev, 256, 256, 256, nullptr, 0, 0, Bo, 256,
                out + (size_t)(T_STEPS - 2) * NN * FOUT, FOUT, bo, nullptr,
                NN, 256, 0, nullptr, nullptr, nullptr, 1, RPG};
  GemmP empty2 = empty;
  combo<<<g2 + g1, blk, 0, stream>>>(C1f, g2, OPm2, g1, empty2, 0);
  GemmP OPm1 = {h1f_last, 256, 256, 256, nullptr, 0, 0, Bo, 256,
                out + (size_t)(T_STEPS - 1) * NN * FOUT, FOUT, bo, nullptr,
                NN, 256, 0, nullptr, nullptr, nullptr, 1, RPG};
  combo<<<g1, blk, 0, stream>>>(OPm1, g1, empty, 0, empty, 0);
}

// Round 12
// 4964.183 us; speedup vs baseline: 2.1074x; 2.1074x over previous
//
#include <hip/hip_runtime.h>
#include <hip/hip_bf16.h>
#include <stdint.h>

#define T_STEPS 12
#define NN 20000
#define NE 320000
#define FIN 128
#define HD 256
#define FOUT 128
#define PADR 96  // pad A-panel buffers to 157*128 = 20096 rows

typedef __attribute__((ext_vector_type(4))) float f32x4;
typedef __attribute__((ext_vector_type(8))) _Float16 f16x8;

static __device__ __forceinline__ float sigmoidf_(float x) {
  return 1.0f / (1.0f + __expf(-x));
}
static __device__ __forceinline__ ushort f2h(float f) {
  union { ushort s; _Float16 h; } v; v.h = (_Float16)f; return v.s;
}

// async global -> LDS, 16B per lane, LDS dest = wave-uniform base + lane*16
static __device__ __forceinline__ void gload_lds16(const _Float16* g, _Float16* l) {
  auto gp = (const __attribute__((address_space(1))) _Float16*)g;
  auto lp = (__attribute__((address_space(3))) _Float16*)l;
  __builtin_amdgcn_global_load_lds(gp, lp, 16, 0, 0);
}

// ---------------- CSR build ----------------
__global__ void count_kernel(const int* __restrict__ dst, int* __restrict__ counts) {
  int e = blockIdx.x * blockDim.x + threadIdx.x;
  if (e < NE) atomicAdd(&counts[dst[e]], 1);
}

__global__ void scan_kernel(const int* __restrict__ counts, int* __restrict__ offs,
                            int* __restrict__ cursor) {
  __shared__ int sm[1024];
  __shared__ int carry_s;
  if (threadIdx.x == 0) carry_s = 0;
  __syncthreads();
  const int n = NN;
  int nch = (n + 1023) >> 10;
  for (int c = 0; c < nch; ++c) {
    int i = (c << 10) + (int)threadIdx.x;
    int v = (i < n) ? counts[i] : 0;
    sm[threadIdx.x] = v;
    __syncthreads();
    for (int off = 1; off < 1024; off <<= 1) {
      int t = (threadIdx.x >= (unsigned)off) ? sm[threadIdx.x - off] : 0;
      __syncthreads();
      sm[threadIdx.x] += t;
      __syncthreads();
    }
    int incl = sm[threadIdx.x];
    int carry_local = carry_s;
    if (i < n) {
      int excl = carry_local + incl - v;
      offs[i] = excl;
      cursor[i] = excl;
    }
    __syncthreads();
    if (threadIdx.x == 1023) carry_s = carry_local + incl;
    __syncthreads();
  }
  if (threadIdx.x == 0) offs[n] = carry_s;
}

__global__ void fill_kernel(const int* __restrict__ src, const int* __restrict__ dst,
                            int* __restrict__ cursor, int* __restrict__ esrc) {
  int e = blockIdx.x * blockDim.x + threadIdx.x;
  if (e < NE) {
    int d = dst[e];
    int pos = atomicAdd(&cursor[d], 1);
    esrc[pos] = src[e];
  }
}

// ---------------- agg body: fp32 gather-sum -> fp16 hi/lo (W=256, out ld=512) ----------------
static __device__ __forceinline__ void agg_body256(int blk, const float* __restrict__ feat,
                                                   const int* __restrict__ offs,
                                                   const int* __restrict__ esrc,
                                                   _Float16* __restrict__ out) {
  int d = blk * 4 + (threadIdx.x >> 6);
  int lane = threadIdx.x & 63;
  int beg = offs[d], end = offs[d + 1];
  float a0[4] = {}, a1[4] = {}, a2[4] = {}, a3[4] = {};
  int e = beg;
  for (; e + 3 < end; e += 4) {
    float4 v0 = *reinterpret_cast<const float4*>(feat + (size_t)esrc[e] * 256 + lane * 4);
    float4 v1 = *reinterpret_cast<const float4*>(feat + (size_t)esrc[e + 1] * 256 + lane * 4);
    float4 v2 = *reinterpret_cast<const float4*>(feat + (size_t)esrc[e + 2] * 256 + lane * 4);
    float4 v3 = *reinterpret_cast<const float4*>(feat + (size_t)esrc[e + 3] * 256 + lane * 4);
    a0[0] += v0.x; a0[1] += v0.y; a0[2] += v0.z; a0[3] += v0.w;
    a1[0] += v1.x; a1[1] += v1.y; a1[2] += v1.z; a1[3] += v1.w;
    a2[0] += v2.x; a2[1] += v2.y; a2[2] += v2.z; a2[3] += v2.w;
    a3[0] += v3.x; a3[1] += v3.y; a3[2] += v3.z; a3[3] += v3.w;
  }
  for (; e < end; ++e) {
    float4 v0 = *reinterpret_cast<const float4*>(feat + (size_t)esrc[e] * 256 + lane * 4);
    a0[0] += v0.x; a0[1] += v0.y; a0[2] += v0.z; a0[3] += v0.w;
  }
  ushort hi[4], lo[4];
#pragma unroll
  for (int p = 0; p < 4; ++p) {
    float a = (a0[p] + a1[p]) + (a2[p] + a3[p]);
    hi[p] = f2h(a);
    union { ushort s; _Float16 h; } u; u.s = hi[p];
    lo[p] = f2h(a - (float)u.h);
  }
  *reinterpret_cast<ushort4*>(out + (size_t)d * 512 + lane * 4) = *reinterpret_cast<ushort4*>(hi);
  *reinterpret_cast<ushort4*>(out + (size_t)d * 512 + 256 + lane * 4) = *reinterpret_cast<ushort4*>(lo);
}

__global__ void agg_split_h(const float* __restrict__ feat, const int* __restrict__ offs,
                            const int* __restrict__ esrc, _Float16* __restrict__ out) {
  agg_body256(blockIdx.x, feat, offs, esrc, out);
}

// dual agg: two independent gathers in one launch (like-resourced merge only)
__global__ void agg_dual(const float* __restrict__ f0, _Float16* __restrict__ o0,
                         const float* __restrict__ f1, _Float16* __restrict__ o1,
                         const int* __restrict__ offs, const int* __restrict__ esrc) {
  if (blockIdx.y == 0) agg_body256(blockIdx.x, f0, offs, esrc, o0);
  else                 agg_body256(blockIdx.x, f1, offs, esrc, o1);
}

// batched x-aggregation over all T steps: grid (NN/4, T); out [t][N][256] = [hi128|lo128]
__global__ void agg_split_x(const float* __restrict__ x, const int* __restrict__ offs,
                            const int* __restrict__ esrc, _Float16* __restrict__ out) {
  int t = blockIdx.y;
  const float* feat = x + (size_t)t * NN * FIN;
  _Float16* o = out + (size_t)t * NN * 256;
  int d = blockIdx.x * 4 + (threadIdx.x >> 6);
  int lane = threadIdx.x & 63;
  int beg = offs[d], end = offs[d + 1];
  float a0[2] = {}, a1[2] = {}, a2[2] = {}, a3[2] = {};
  int e = beg;
  for (; e + 3 < end; e += 4) {
    float2 v0 = *reinterpret_cast<const float2*>(feat + (size_t)esrc[e] * FIN + lane * 2);
    float2 v1 = *reinterpret_cast<const float2*>(feat + (size_t)esrc[e + 1] * FIN + lane * 2);
    float2 v2 = *reinterpret_cast<const float2*>(feat + (size_t)esrc[e + 2] * FIN + lane * 2);
    float2 v3 = *reinterpret_cast<const float2*>(feat + (size_t)esrc[e + 3] * FIN + lane * 2);
    a0[0] += v0.x; a0[1] += v0.y; a1[0] += v1.x; a1[1] += v1.y;
    a2[0] += v2.x; a2[1] += v2.y; a3[0] += v3.x; a3[1] += v3.y;
  }
  for (; e < end; ++e) {
    float2 v0 = *reinterpret_cast<const float2*>(feat + (size_t)esrc[e] * FIN + lane * 2);
    a0[0] += v0.x; a0[1] += v0.y;
  }
  float s0 = (a0[0] + a1[0]) + (a2[0] + a3[0]);
  float s1 = (a0[1] + a1[1]) + (a2[1] + a3[1]);
  ushort2 hi, lo;
  hi.x = f2h(s0); hi.y = f2h(s1);
  union { ushort s; _Float16 h; } u0, u1;
  u0.s = hi.x; u1.s = hi.y;
  lo.x = f2h(s0 - (float)u0.h); lo.y = f2h(s1 - (float)u1.h);
  *reinterpret_cast<ushort2*>(o + (size_t)d * 256 + lane * 2) = hi;
  *reinterpret_cast<ushort2*>(o + (size_t)d * 256 + FIN + lane * 2) = lo;
}

// ---------------- fp16 MFMA GEMM (R9 math, global_load_lds staging) ----------------
// Logical A col k: k < lenA -> Aa col (k>=wrapA ? k-wrapA : k); else Ab with wrapB.
// mode 0: C = acc + bias. mode 1 (fused r/u): v = acc + bias; cols<256 -> rh=sigmoid(v)*h;
// 256..511 -> C=sigmoid(v); >=512 -> C=v. mode 2: nh = u*h + (1-u)*tanh(xw_c + acc) -> h (+hf).
// A-panel sources MUST be padded to 20096 rows (loads are unpredicated); epilogue masks m<M.
__global__ __launch_bounds__(256) void gemm_f16(
    const _Float16* __restrict__ Aa, int lda_a, int wrapA, int lenA,
    const _Float16* __restrict__ Ab, int lda_b, int wrapB,
    const _Float16* __restrict__ B, int ldb,
    float* __restrict__ C, int ldc, const float* __restrict__ bias,
    int M, int K, int mode, float* __restrict__ h, _Float16* __restrict__ hf,
    float* __restrict__ rh, int nch, int rpg) {
  __shared__ _Float16 As[128 * 64];
  __shared__ _Float16 Bs[128 * 64];

  int p = blockIdx.x;
  int xcd = p & 7;
  int q = p >> 3;
  int rowt = xcd * rpg + q / nch;
  int chunk = q % nch;
  int m0 = rowt * 128;
  if (m0 >= M) return;
  int n0 = chunk * 128;

  int tid = threadIdx.x;
  int wave = tid >> 6;
  int lane = tid & 63;
  int wm = wave >> 1, wn = wave & 1;
  int lrow = lane & 15;
  int kgrp = lane >> 4;

  f32x4 acc[4][4] = {};

  // staging coords: wave stages rows wave*32 .. +31 (4 insts of 8 rows, 1KB each).
  // LDS write is linear (HW: base + lane*16); the XOR swizzle is applied to the
  // GLOBAL source column instead: elem = 8*((lane&7) ^ (lane>>3))  [rule 21 / m173]
  int row8 = lane >> 3;                       // 0..7 row within 8-row group
  int swz8 = 8 * ((lane & 7) ^ row8);         // pre-swizzled source elem offset
  int wrow = wave * 32;

  for (int k0 = 0; k0 < K; k0 += 64) {
    const _Float16* Abase;
    int ka, ldA;
    if (k0 < lenA) {
      ka = (k0 >= wrapA) ? k0 - wrapA : k0;
      Abase = Aa; ldA = lda_a;
    } else {
      int kp = k0 - lenA;
      ka = (kp >= wrapB) ? kp - wrapB : kp;
      Abase = Ab; ldA = lda_b;
    }
    __syncthreads();  // prior tile's ds_reads complete before overwrite
#pragma unroll
    for (int p4 = 0; p4 < 4; ++p4) {
      int r = wrow + p4 * 8;  // wave-uniform base row of this 8-row group
      gload_lds16(&Abase[(size_t)(m0 + r + row8) * ldA + ka + swz8], &As[r * 64]);
      gload_lds16(&B[(size_t)(n0 + r + row8) * ldb + k0 + swz8], &Bs[r * 64]);
    }
    __syncthreads();  // compiler drains vmcnt(0) before barrier -> LDS ready

#pragma unroll
    for (int kk = 0; kk < 2; ++kk) {
      f16x8 af[4], bf[4];
      int kbyte = kk * 64 + kgrp * 16;
#pragma unroll
      for (int i = 0; i < 4; ++i) {
        int ar = wm * 64 + i * 16 + lrow;
        af[i] = *reinterpret_cast<const f16x8*>(
            reinterpret_cast<const char*>(As) + ar * 128 + (kbyte ^ ((ar & 7) << 4)));
        int br = wn * 64 + i * 16 + lrow;
        bf[i] = *reinterpret_cast<const f16x8*>(
            reinterpret_cast<const char*>(Bs) + br * 128 + (kbyte ^ ((br & 7) << 4)));
      }
      // operand-swapped: lane's 4 acc regs = 4 consecutive output COLUMNS
#pragma unroll
      for (int i = 0; i < 4; ++i)
#pragma unroll
        for (int j = 0; j < 4; ++j)
          acc[i][j] = __builtin_amdgcn_mfma_f32_16x16x32_f16(bf[j], af[i], acc[i][j], 0, 0, 0);
    }
  }

  // epilogue: acc[i][j][r] -> row m0+wm*64+i*16+lrow, col n0+wn*64+j*16+kgrp*4+r
#pragma unroll
  for (int i = 0; i < 4; ++i) {
    int m = m0 + wm * 64 + i * 16 + lrow;
    if (m >= M) continue;
#pragma unroll
    for (int j = 0; j < 4; ++j) {
      int colbase = n0 + wn * 64 + j * 16 + kgrp * 4;
      f32x4 v = acc[i][j];
      if (mode == 0) {
        float4 bv4 = *reinterpret_cast<const float4*>(&bias[colbase]);
        v[0] += bv4.x; v[1] += bv4.y; v[2] += bv4.z; v[3] += bv4.w;
        *reinterpret_cast<f32x4*>(&C[(size_t)m * ldc + colbase]) = v;
      } else if (mode == 1) {
        float4 bv4 = *reinterpret_cast<const float4*>(&bias[colbase]);
        v[0] += bv4.x; v[1] += bv4.y; v[2] += bv4.z; v[3] += bv4.w;
        if (colbase < 256) {
          float4 hv = *reinterpret_cast<const float4*>(&h[(size_t)m * 256 + colbase]);
          f32x4 rv;
          rv[0] = sigmoidf_(v[0]) * hv.x;
          rv[1] = sigmoidf_(v[1]) * hv.y;
          rv[2] = sigmoidf_(v[2]) * hv.z;
          rv[3] = sigmoidf_(v[3]) * hv.w;
          *reinterpret_cast<f32x4*>(&rh[(size_t)m * 256 + colbase]) = rv;
        } else if (colbase < 512) {
          v[0] = sigmoidf_(v[0]); v[1] = sigmoidf_(v[1]);
          v[2] = sigmoidf_(v[2]); v[3] = sigmoidf_(v[3]);
          *reinterpret_cast<f32x4*>(&C[(size_t)m * ldc + colbase]) = v;
        } else {
          *reinterpret_cast<f32x4*>(&C[(size_t)m * ldc + colbase]) = v;
        }
      } else {
        float4 xc = *reinterpret_cast<const float4*>(&C[(size_t)m * ldc + 512 + colbase]);
        float4 uu = *reinterpret_cast<const float4*>(&C[(size_t)m * ldc + 256 + colbase]);
        float* hp = &h[(size_t)m * 256 + colbase];
        float4 hv = *reinterpret_cast<const float4*>(hp);
        float4 nh;
        nh.x = uu.x * hv.x + (1.f - uu.x) * tanhf(xc.x + v[0]);
        nh.y = uu.y * hv.y + (1.f - uu.y) * tanhf(xc.y + v[1]);
        nh.z = uu.z * hv.z + (1.f - uu.z) * tanhf(xc.z + v[2]);
        nh.w = uu.w * hv.w + (1.f - uu.w) * tanhf(xc.w + v[3]);
        *reinterpret_cast<float4*>(hp) = nh;
        if (hf) {
          ushort4 hv16;
          hv16.x = f2h(nh.x); hv16.y = f2h(nh.y);
          hv16.z = f2h(nh.z); hv16.w = f2h(nh.w);
          *reinterpret_cast<ushort4*>(&hf[(size_t)m * 256 + colbase]) = hv16;
        }
      }
    }
  }
}

// ---------------- weight prep ----------------
__global__ void wtrans(const float* __restrict__ W, _Float16* __restrict__ dst,
                       int K, int ldw, int ldd, int koff, int mode) {
  int k = blockIdx.x * blockDim.x + threadIdx.x;
  int n = blockIdx.y;
  if (k < K) {
    float w = W[(size_t)k * ldw + n];
    _Float16 hi = (_Float16)w;
    dst[(size_t)n * ldd + koff + k] = mode ? (_Float16)(w - (float)hi) : hi;
  }
}

__global__ void bias_comb(const float* __restrict__ bx, const float* __restrict__ bh,
                          float* __restrict__ out) {
  int i = blockIdx.x * blockDim.x + threadIdx.x;
  if (i < 768) out[i] = bx[i] + bh[i];
}

__global__ void copy_kernel(const float* __restrict__ in, float* __restrict__ out, int n4) {
  int i = blockIdx.x * blockDim.x + threadIdx.x;
  if (i < n4) reinterpret_cast<float4*>(out)[i] = reinterpret_cast<const float4*>(in)[i];
}

// ---------------- host ----------------
extern "C" void kernel_launch(void* const* d_in, const int* in_sizes, int n_in,
                              void* d_out, int out_size, void* d_ws, size_t ws_size,
                              hipStream_t stream) {
  const float* x   = (const float*)d_in[0];
  const float* h0  = (const float*)d_in[1];
  const int*   src = (const int*)d_in[2];
  const int*   dst = (const int*)d_in[3];
  const float* Wx0 = (const float*)d_in[4];
  const float* bx0 = (const float*)d_in[5];
  const float* Wh0 = (const float*)d_in[6];
  const float* bh0 = (const float*)d_in[7];
  const float* Wx1 = (const float*)d_in[8];
  const float* bx1 = (const float*)d_in[9];
  const float* Wh1 = (const float*)d_in[10];
  const float* bh1 = (const float*)d_in[11];
  const float* Wo  = (const float*)d_in[12];
  const float* bo  = (const float*)d_in[13];
  float* out = (float*)d_out;

  char* p = (char*)d_ws;
  auto alloc = [&](size_t bytes) {
    char* r = p;
    p += (bytes + 255) & ~(size_t)255;
    return r;
  };
  int* offs   = (int*)alloc((NN + 1) * sizeof(int));
  int* cursor = (int*)alloc(NN * sizeof(int));
  int* counts = (int*)alloc(NN * sizeof(int));
  int* esrc   = (int*)alloc(NE * sizeof(int));
  // B panels [N][K] fp16, 3-term K layout per source: [Whi | Whi | Wlo]
  _Float16* B0  = (_Float16*)alloc((size_t)768 * 1152 * 2);
  _Float16* B0h = (_Float16*)alloc((size_t)256 * 768 * 2);
  _Float16* B1  = (_Float16*)alloc((size_t)768 * 1536 * 2);
  _Float16* B1h = (_Float16*)alloc((size_t)256 * 768 * 2);
  _Float16* Bo  = (_Float16*)alloc((size_t)128 * 256 * 2);
  float* b0c  = (float*)alloc(768 * 4);
  float* b1c  = (float*)alloc(768 * 4);
  // A-panel buffers padded to 20096 rows (unpredicated gload_lds reads)
  _Float16* XAGG  = (_Float16*)alloc(((size_t)T_STEPS * NN + PADR) * 256 * 2);
  _Float16* H0AGG = (_Float16*)alloc((size_t)(NN + PADR) * 512 * 2);
  _Float16* H1AGG = (_Float16*)alloc((size_t)(NN + PADR) * 512 * 2);
  _Float16* RHAGG = (_Float16*)alloc((size_t)(NN + PADR) * 512 * 2);
  _Float16* h1f   = (_Float16*)alloc((size_t)(NN + PADR) * 256 * 2);
  float* rhf  = (float*)alloc((size_t)NN * 256 * 4);
  float* xw   = (float*)alloc((size_t)NN * 768 * 4);

  // fp32 GRU states live directly in d_out tail
  float* h0c = out + (size_t)T_STEPS * NN * FOUT;
  float* h1c = h0c + (size_t)NN * HD;

  // CSR
  hipMemsetAsync(counts, 0, NN * sizeof(int), stream);
  count_kernel<<<(NE + 255) / 256, 256, 0, stream>>>(dst, counts);
  scan_kernel<<<1, 1024, 0, stream>>>(counts, offs, cursor);
  fill_kernel<<<(NE + 255) / 256, 256, 0, stream>>>(src, dst, cursor, esrc);

  // weight prep (c-gate rows keep all-zero h-part; c h-term via B0h/B1h GEMM)
  hipMemsetAsync(B0, 0, (size_t)768 * 1152 * 2, stream);
  hipMemsetAsync(B1, 0, (size_t)768 * 1536 * 2, stream);
  for (int g = 0; g < 3; ++g) {
    const float* W = Wx0 + (size_t)g * 128 * 256;
    _Float16* D = B0 + (size_t)g * 256 * 1152;
    wtrans<<<dim3(1, 256), 256, 0, stream>>>(W, D, 128, 256, 1152, 0, 0);
    wtrans<<<dim3(1, 256), 256, 0, stream>>>(W, D, 128, 256, 1152, 128, 0);
    wtrans<<<dim3(1, 256), 256, 0, stream>>>(W, D, 128, 256, 1152, 256, 1);
  }
  for (int g = 0; g < 2; ++g) {
    const float* W = Wh0 + (size_t)g * 256 * 256;
    _Float16* D = B0 + (size_t)g * 256 * 1152;
    wtrans<<<dim3(1, 256), 256, 0, stream>>>(W, D, 256, 256, 1152, 384, 0);
    wtrans<<<dim3(1, 256), 256, 0, stream>>>(W, D, 256, 256, 1152, 640, 0);
    wtrans<<<dim3(1, 256), 256, 0, stream>>>(W, D, 256, 256, 1152, 896, 1);
  }
  {
    const float* W = Wh0 + (size_t)2 * 256 * 256;
    wtrans<<<dim3(1, 256), 256, 0, stream>>>(W, B0h, 256, 256, 768, 0, 0);
    wtrans<<<dim3(1, 256), 256, 0, stream>>>(W, B0h, 256, 256, 768, 256, 0);
    wtrans<<<dim3(1, 256), 256, 0, stream>>>(W, B0h, 256, 256, 768, 512, 1);
  }
  for (int g = 0; g < 3; ++g) {
    const float* W = Wx1 + (size_t)g * 256 * 256;
    _Float16* D = B1 + (size_t)g * 256 * 1536;
    wtrans<<<dim3(1, 256), 256, 0, stream>>>(W, D, 256, 256, 1536, 0, 0);
    wtrans<<<dim3(1, 256), 256, 0, stream>>>(W, D, 256, 256, 1536, 256, 0);
    wtrans<<<dim3(1, 256), 256, 0, stream>>>(W, D, 256, 256, 1536, 512, 1);
  }
  for (int g = 0; g < 2; ++g) {
    const float* W = Wh1 + (size_t)g * 256 * 256;
    _Float16* D = B1 + (size_t)g * 256 * 1536;
    wtrans<<<dim3(1, 256), 256, 0, stream>>>(W, D, 256, 256, 1536, 768, 0);
    wtrans<<<dim3(1, 256), 256, 0, stream>>>(W, D, 256, 256, 1536, 1024, 0);
    wtrans<<<dim3(1, 256), 256, 0, stream>>>(W, D, 256, 256, 1536, 1280, 1);
  }
  {
    const float* W = Wh1 + (size_t)2 * 256 * 256;
    wtrans<<<dim3(1, 256), 256, 0, stream>>>(W, B1h, 256, 256, 768, 0, 0);
    wtrans<<<dim3(1, 256), 256, 0, stream>>>(W, B1h, 256, 256, 768, 256, 0);
    wtrans<<<dim3(1, 256), 256, 0, stream>>>(W, B1h, 256, 256, 768, 512, 1);
  }
  wtrans<<<dim3(1, 128), 256, 0, stream>>>(Wo, Bo, 256, 128, 256, 0, 0);
  bias_comb<<<3, 256, 0, stream>>>(bx0, bh0, b0c);
  bias_comb<<<3, 256, 0, stream>>>(bx1, bh1, b1c);

  copy_kernel<<<(2 * NN * HD / 4 + 255) / 256, 256, 0, stream>>>(h0, h0c, 2 * NN * HD / 4);

  dim3 blk(256);
  const int RPG = 20;
  int g6 = 8 * RPG * 6, g2 = 8 * RPG * 2, g1 = 8 * RPG * 1;
  int agg_grid = NN / 4;

  agg_split_x<<<dim3(agg_grid, T_STEPS), blk, 0, stream>>>(x, offs, esrc, XAGG);
  agg_split_h<<<agg_grid, blk, 0, stream>>>(h0c, offs, esrc, H0AGG);

  for (int t = 0; t < T_STEPS; ++t) {
    // ---- 1: L0 (K=1152, fused r/u) ----
    gemm_f16<<<g6, blk, 0, stream>>>(XAGG + (size_t)t * NN * 256, 256, 256, 384,
                                     H0AGG, 512, 512, B0, 1152, xw, 768, b0c,
                                     NN, 1152, 1, h0c, nullptr, rhf, 6, RPG);
    // ---- 2: agg(rhf→RHAGG) ∥ agg(h1c→H1AGG) ----
    agg_dual<<<dim3(agg_grid, 2), blk, 0, stream>>>(rhf, RHAGG, h1c, H1AGG, offs, esrc);
    // ---- 3: c0 (K=768, fused state update -> h0c) ----
    gemm_f16<<<g2, blk, 0, stream>>>(RHAGG, 512, 512, 768, nullptr, 0, 0,
                                     B0h, 768, xw, 768, nullptr,
                                     NN, 768, 2, h0c, nullptr, nullptr, 2, RPG);
    // ---- 4: agg(h0c→H0AGG) (feeds L1 and next step's L0) ----
    agg_split_h<<<agg_grid, blk, 0, stream>>>(h0c, offs, esrc, H0AGG);
    // ---- 5: L1 (K=1536, fused r/u) ----
    gemm_f16<<<g6, blk, 0, stream>>>(H0AGG, 512, 512, 768, H1AGG, 512, 512,
                                     B1, 1536, xw, 768, b1c,
                                     NN, 1536, 1, h1c, nullptr, rhf, 6, RPG);
    // ---- 6: agg(rhf→RHAGG) ----
    agg_split_h<<<agg_grid, blk, 0, stream>>>(rhf, offs, esrc, RHAGG);
    // ---- 7: c1 (K=768, fused state update -> h1c + fp16 mirror) ----
    gemm_f16<<<g2, blk, 0, stream>>>(RHAGG, 512, 512, 768, nullptr, 0, 0,
                                     B1h, 768, xw, 768, nullptr,
                                     NN, 768, 2, h1c, h1f, nullptr, 2, RPG);
    // ---- 8: output projection (K=256 single-term) ----
    gemm_f16<<<g1, blk, 0, stream>>>(h1f, 256, 256, 256, nullptr, 0, 0,
                                     Bo, 256, out + (size_t)t * NN * FOUT, FOUT, bo,
                                     NN, 256, 0, nullptr, nullptr, nullptr, 1, RPG);
  }
}